// Round 1
// baseline (1547.758 us; speedup 1.0000x reference)
//
#include <hip/hip_runtime.h>
#include <hip/hip_bf16.h>
#include <cstdint>

// MHRetention: x[4,4096,2048] ; Wq,Wk,Wv,Wu,Wo [2048,2048] (stored [in,out])
// q,k = relu(xW)/sqrt(128); u = silu(xWu); kv = sum_l k^T v per (b,h);
// o = srms_norm(q @ kv) * u ; y = o @ Wo
//
// N=16384 tokens, D=2048, H=16, dh=128.

typedef __attribute__((ext_vector_type(8))) short short8;
typedef __attribute__((ext_vector_type(4))) float f32x4;

#define DEVI static __device__ __forceinline__

DEVI float bf2f(unsigned short u) {
    union { unsigned int i; float f; } w; w.i = ((unsigned int)u) << 16; return w.f;
}
DEVI unsigned short f2bf(float f) {
    union { float f; unsigned int i; } w; w.f = f;
    return (unsigned short)((w.i + 0x7fffu + ((w.i >> 16) & 1u)) >> 16);  // RNE
}

// global -> LDS direct DMA, 16B per lane. LDS dest is wave-uniform base + lane*16.
#define GLDS16(gp, lp) __builtin_amdgcn_global_load_lds( \
    (const __attribute__((address_space(1))) void*)(gp), \
    (__attribute__((address_space(3))) void*)(lp), 16, 0, 0)

// ---------------------------------------------------------------- dtype probe
// Reinterpret first 4096 ushorts of x as bf16. True bf16 N(0,1) data: ~0
// extreme exponents. fp32 data: mantissa low-halves have random exponent
// fields -> ~22% extremes. flag=1 => inputs are bf16.
__global__ void probe_dtype(const unsigned short* __restrict__ x, int* flag) {
    __shared__ int cnt;
    if (threadIdx.x == 0) cnt = 0;
    __syncthreads();
    int c = 0;
    for (int i = threadIdx.x; i < 4096; i += 256) {
        float a = fabsf(bf2f(x[i]));
        if (!(a <= 1e4f) || (a != 0.0f && a < 1e-4f)) ++c;  // NaN -> first test true
    }
    atomicAdd(&cnt, c);
    __syncthreads();
    if (threadIdx.x == 0) *flag = (cnt < 512) ? 1 : 0;
}

// ------------------------------------------------- weight transpose + convert
// Wt4 rows [z*2048 + j], cols k : = W_z[k][j], bf16.  z=4 -> Wot.
__global__ void wconvert(const void* __restrict__ Wq, const void* __restrict__ Wk,
                         const void* __restrict__ Wv, const void* __restrict__ Wu,
                         const void* __restrict__ Wo,
                         unsigned short* __restrict__ wt4,
                         unsigned short* __restrict__ wot,
                         const int* __restrict__ flag) {
    const int z = blockIdx.z;
    const void* W = (z == 0) ? Wq : (z == 1) ? Wk : (z == 2) ? Wv : (z == 3) ? Wu : Wo;
    const bool isbf = (*flag != 0);
    __shared__ float tile[32][33];
    const int j0 = blockIdx.x * 32, i0 = blockIdx.y * 32;
    const int tx = threadIdx.x, ty = threadIdx.y;  // (32,8)
#pragma unroll
    for (int r = 0; r < 4; ++r) {
        const int i = i0 + ty * 4 + r;
        float v;
        if (isbf) v = bf2f(((const unsigned short*)W)[i * 2048 + j0 + tx]);
        else      v = ((const float*)W)[i * 2048 + j0 + tx];
        tile[ty * 4 + r][tx] = v;
    }
    __syncthreads();
#pragma unroll
    for (int r = 0; r < 4; ++r) {
        const int j = j0 + ty * 4 + r;
        const unsigned short bv = f2bf(tile[tx][ty * 4 + r]);  // = W[i0+tx][j]
        if (z < 4) wt4[(long)(z * 2048 + j) * 2048 + i0 + tx] = bv;
        else       wot[(long)j * 2048 + i0 + tx] = bv;
    }
}

// ------------------------------------------------------------- x -> bf16
__global__ void xconvert(const void* __restrict__ X, unsigned short* __restrict__ xb,
                         const int* __restrict__ flag) {
    const bool isbf = (*flag != 0);
    const long i = (long)blockIdx.x * 256 + threadIdx.x;  // 4,194,304 threads x 8 elems
    if (isbf) {
        ((uint4*)xb)[i] = ((const uint4*)X)[i];
    } else {
        const float4 f0 = ((const float4*)X)[2 * i];
        const float4 f1 = ((const float4*)X)[2 * i + 1];
        union { unsigned short us[8]; uint4 v; } o;
        o.us[0] = f2bf(f0.x); o.us[1] = f2bf(f0.y); o.us[2] = f2bf(f0.z); o.us[3] = f2bf(f0.w);
        o.us[4] = f2bf(f1.x); o.us[5] = f2bf(f1.y); o.us[6] = f2bf(f1.z); o.us[7] = f2bf(f1.w);
        ((uint4*)xb)[i] = o.v;
    }
}

// ---------------------------------------------- fused QKVU projection GEMM
// C[m,j] = sum_k Xb[m,k] * Wt4[j,k],  m<16384, j<8192, K=2048.
// m97 structure: 128x128 tile, BK=32, 4 waves (2x2 of 64x64), 16x16x32 MFMA.
// Epilogue: segment j>>11 selects {Q: relu/s, K: relu/s, V: id, U: silu}.
__global__ void gemm_qkvu(const unsigned short* __restrict__ Xb,
                          const unsigned short* __restrict__ Wt4,
                          unsigned short* __restrict__ Qb, unsigned short* __restrict__ Kb,
                          unsigned short* __restrict__ Vb, unsigned short* __restrict__ Ub) {
    __shared__ unsigned short As[128 * 32];
    __shared__ unsigned short Bs[128 * 32];
    const int tid = threadIdx.x;
    const int wave = tid >> 6, lane = tid & 63;
    const int m0 = blockIdx.x * 128;
    const int nt = blockIdx.y;            // 0..63
    const int j0 = nt * 128;
    const int wr = wave >> 1, wc = wave & 1;
    const int srow = tid >> 2;            // staging row 0..63
    const int scol = (tid & 3) * 8;       // staging col (elements)
    f32x4 acc[4][4] = {};

    for (int kt = 0; kt < 64; ++kt) {
        __syncthreads();
        const int kb = kt * 32;
#pragma unroll
        for (int i = 0; i < 2; ++i) {
            GLDS16(Xb  + (long)(m0 + i * 64 + srow) * 2048 + kb + scol, As + i * 2048 + wave * 512);
            GLDS16(Wt4 + (long)(j0 + i * 64 + srow) * 2048 + kb + scol, Bs + i * 2048 + wave * 512);
        }
        __syncthreads();
        short8 a[4], b[4];
#pragma unroll
        for (int fm = 0; fm < 4; ++fm)
            a[fm] = *(const short8*)(As + (wr * 64 + fm * 16 + (lane & 15)) * 32 + (lane >> 4) * 8);
#pragma unroll
        for (int fn = 0; fn < 4; ++fn)
            b[fn] = *(const short8*)(Bs + (wc * 64 + fn * 16 + (lane & 15)) * 32 + (lane >> 4) * 8);
#pragma unroll
        for (int fm = 0; fm < 4; ++fm)
#pragma unroll
            for (int fn = 0; fn < 4; ++fn)
                acc[fm][fn] = __builtin_amdgcn_mfma_f32_16x16x32_bf16(a[fm], b[fn], acc[fm][fn], 0, 0, 0);
    }

    const int seg = nt >> 4;  // 0..3
    unsigned short* outp = (seg == 0) ? Qb : (seg == 1) ? Kb : (seg == 2) ? Vb : Ub;
    const int cl0 = (nt & 15) * 128 + wc * 64;
#pragma unroll
    for (int fm = 0; fm < 4; ++fm) {
#pragma unroll
        for (int fn = 0; fn < 4; ++fn) {
            const int col = cl0 + fn * 16 + (lane & 15);
#pragma unroll
            for (int r = 0; r < 4; ++r) {
                const long row = m0 + wr * 64 + fm * 16 + ((lane >> 4) << 2) + r;
                float v = acc[fm][fn][r];
                if (seg <= 1)      v = fmaxf(v, 0.0f) * 0.08838834764831845f;  // relu/sqrt(128)
                else if (seg == 3) v = v / (1.0f + __expf(-v));                // silu
                outp[row * 2048 + col] = f2bf(v);
            }
        }
    }
}

// --------------------------------------------- KV state: kv[dk,dv] = sum_l k*v
// Stored TRANSPOSED as KVt[bh][dv][dk] (fp32) so the Q@KV GEMM's B-operand
// reads are k-contiguous. LDS-staged VALU outer product, fp32 atomics.
__global__ void kv_accum(const unsigned short* __restrict__ Kb,
                         const unsigned short* __restrict__ Vb,
                         float* __restrict__ KVt) {
    const int bh = blockIdx.x;           // 64
    const int b = bh >> 4, h = bh & 15;
    const int chunk = blockIdx.y;        // 8 chunks of 512 rows
    const int t = threadIdx.x;
    __shared__ float ks[16][128];
    __shared__ float vs[16][128];
    float acc[8][8] = {};
    const int rb = t >> 4, cb = t & 15;  // rows dk=rb*8.., cols dv=cb*8..
    const long base = ((long)b * 4096 + chunk * 512) * 2048 + h * 128;
    const int dd = t & 127;
    const unsigned short* src = (t < 128) ? Kb : Vb;  // wave-uniform (waves 0,1 vs 2,3)

    for (int it = 0; it < 32; ++it) {
        __syncthreads();
#pragma unroll
        for (int r = 0; r < 16; ++r) {
            const float v = bf2f(src[base + (long)(it * 16 + r) * 2048 + dd]);
            if (t < 128) ks[r][dd] = v; else vs[r][dd] = v;
        }
        __syncthreads();
#pragma unroll
        for (int r = 0; r < 16; ++r) {
            float kk[8], vv[8];
#pragma unroll
            for (int i = 0; i < 8; ++i) kk[i] = ks[r][rb * 8 + i];
#pragma unroll
            for (int j = 0; j < 8; ++j) vv[j] = vs[r][cb * 8 + j];
#pragma unroll
            for (int i = 0; i < 8; ++i)
#pragma unroll
                for (int j = 0; j < 8; ++j) acc[i][j] += kk[i] * vv[j];
        }
    }
    float* dst = KVt + (long)bh * 16384;
#pragma unroll
    for (int i = 0; i < 8; ++i)
#pragma unroll
        for (int j = 0; j < 8; ++j)
            atomicAdd(&dst[(cb * 8 + j) * 128 + (rb * 8 + i)], acc[i][j]);
}

// ------------------------- O = Q @ KV, SRMS-norm over dh, * u, -> bf16 Ob
// KV consumed as bf16 hi+lo split (2 MFMAs) to keep fp32 state precision.
__global__ void o_norm(const unsigned short* __restrict__ Qb,
                       const unsigned short* __restrict__ Ub,
                       const float* __restrict__ KVt,
                       unsigned short* __restrict__ Ob) {
    __shared__ unsigned short Qs[128 * 128];
    const int tid = threadIdx.x, wave = tid >> 6, lane = tid & 63;
    const int tile = blockIdx.x;   // 0..31 (128-token tiles within one b)
    const int bh = blockIdx.y;     // 0..63
    const int b = bh >> 4, h = bh & 15;
    const long n0 = (long)b * 4096 + tile * 128;

    // stage Q tile [128 tokens][128 dh] via global_load_lds (8 x 4KB issues)
    const int qrow = tid >> 4;          // 0..15
    const int qcol = (tid & 15) * 8;    // elements
#pragma unroll
    for (int i = 0; i < 8; ++i)
        GLDS16(Qb + (n0 + i * 16 + qrow) * 2048 + h * 128 + qcol, Qs + i * 2048 + wave * 512);
    __syncthreads();

    const float* KVrow = KVt + (long)bh * 16384;
    f32x4 acc[2][8] = {};
#pragma unroll
    for (int kk = 0; kk < 4; ++kk) {
        const short8 a0 = *(const short8*)(Qs + (wave * 32 + (lane & 15)) * 128 + kk * 32 + (lane >> 4) * 8);
        const short8 a1 = *(const short8*)(Qs + (wave * 32 + 16 + (lane & 15)) * 128 + kk * 32 + (lane >> 4) * 8);
#pragma unroll
        for (int fn = 0; fn < 8; ++fn) {
            const float* kvb = KVrow + (fn * 16 + (lane & 15)) * 128 + kk * 32 + (lane >> 4) * 8;
            const float4 f0 = *(const float4*)kvb;
            const float4 f1 = *(const float4*)(kvb + 4);
            const float fs[8] = {f0.x, f0.y, f0.z, f0.w, f1.x, f1.y, f1.z, f1.w};
            short8 bhi, blo;
#pragma unroll
            for (int j = 0; j < 8; ++j) {
                const unsigned short hh = f2bf(fs[j]);
                bhi[j] = (short)hh;
                blo[j] = (short)f2bf(fs[j] - bf2f(hh));
            }
            acc[0][fn] = __builtin_amdgcn_mfma_f32_16x16x32_bf16(a0, bhi, acc[0][fn], 0, 0, 0);
            acc[0][fn] = __builtin_amdgcn_mfma_f32_16x16x32_bf16(a0, blo, acc[0][fn], 0, 0, 0);
            acc[1][fn] = __builtin_amdgcn_mfma_f32_16x16x32_bf16(a1, bhi, acc[1][fn], 0, 0, 0);
            acc[1][fn] = __builtin_amdgcn_mfma_f32_16x16x32_bf16(a1, blo, acc[1][fn], 0, 0, 0);
        }
    }

    // per-row (dh=128) sum of squares: lane partial over fn, then 16-lane reduce
#pragma unroll
    for (int fm = 0; fm < 2; ++fm) {
#pragma unroll
        for (int r = 0; r < 4; ++r) {
            float ssq = 0.0f;
#pragma unroll
            for (int fn = 0; fn < 8; ++fn) { const float v = acc[fm][fn][r]; ssq += v * v; }
            ssq += __shfl_xor(ssq, 1);
            ssq += __shfl_xor(ssq, 2);
            ssq += __shfl_xor(ssq, 4);
            ssq += __shfl_xor(ssq, 8);
            const float nrm = fmaxf(sqrtf(ssq) * 0.08838834764831845f, 1e-12f);
            const float scl = 1.0f / nrm;
            const long row = n0 + wave * 32 + fm * 16 + ((lane >> 4) << 2) + r;
#pragma unroll
            for (int fn = 0; fn < 8; ++fn) {
                const int col = fn * 16 + (lane & 15);
                const float uv = bf2f(Ub[row * 2048 + h * 128 + col]);
                Ob[row * 2048 + h * 128 + col] = f2bf(acc[fm][fn][r] * scl * uv);
            }
        }
    }
}

// ------------------------------------------------------- output projection
__global__ void gemm_out(const unsigned short* __restrict__ Obuf,
                         const unsigned short* __restrict__ Wot,
                         void* __restrict__ out, const int* __restrict__ flag) {
    __shared__ unsigned short As[128 * 32];
    __shared__ unsigned short Bs[128 * 32];
    const int tid = threadIdx.x;
    const int wave = tid >> 6, lane = tid & 63;
    const int m0 = blockIdx.x * 128;
    const int j0 = blockIdx.y * 128;  // 0..15 tiles
    const int wr = wave >> 1, wc = wave & 1;
    const int srow = tid >> 2;
    const int scol = (tid & 3) * 8;
    f32x4 acc[4][4] = {};

    for (int kt = 0; kt < 64; ++kt) {
        __syncthreads();
        const int kb = kt * 32;
#pragma unroll
        for (int i = 0; i < 2; ++i) {
            GLDS16(Obuf + (long)(m0 + i * 64 + srow) * 2048 + kb + scol, As + i * 2048 + wave * 512);
            GLDS16(Wot  + (long)(j0 + i * 64 + srow) * 2048 + kb + scol, Bs + i * 2048 + wave * 512);
        }
        __syncthreads();
        short8 a[4], b[4];
#pragma unroll
        for (int fm = 0; fm < 4; ++fm)
            a[fm] = *(const short8*)(As + (wr * 64 + fm * 16 + (lane & 15)) * 32 + (lane >> 4) * 8);
#pragma unroll
        for (int fn = 0; fn < 4; ++fn)
            b[fn] = *(const short8*)(Bs + (wc * 64 + fn * 16 + (lane & 15)) * 32 + (lane >> 4) * 8);
#pragma unroll
        for (int fm = 0; fm < 4; ++fm)
#pragma unroll
            for (int fn = 0; fn < 4; ++fn)
                acc[fm][fn] = __builtin_amdgcn_mfma_f32_16x16x32_bf16(a[fm], b[fn], acc[fm][fn], 0, 0, 0);
    }

    const bool isbf = (*flag != 0);
#pragma unroll
    for (int fm = 0; fm < 4; ++fm) {
#pragma unroll
        for (int fn = 0; fn < 4; ++fn) {
            const int col = j0 + wc * 64 + fn * 16 + (lane & 15);
#pragma unroll
            for (int r = 0; r < 4; ++r) {
                const long row = m0 + wr * 64 + fm * 16 + ((lane >> 4) << 2) + r;
                const float v = acc[fm][fn][r];
                if (isbf) ((unsigned short*)out)[row * 2048 + col] = f2bf(v);
                else      ((float*)out)[row * 2048 + col] = v;
            }
        }
    }
}

// ---------------------------------------------------------------- launcher
extern "C" void kernel_launch(void* const* d_in, const int* in_sizes, int n_in,
                              void* d_out, int out_size, void* d_ws, size_t ws_size,
                              hipStream_t stream) {
    (void)in_sizes; (void)n_in; (void)out_size; (void)ws_size;
    char* ws = (char*)d_ws;
    // workspace layout (bytes); total ~382 MB
    unsigned short* Xb  = (unsigned short*)(ws + 0);           // 67,108,864
    unsigned short* Wt4 = (unsigned short*)(ws + 67108864);    // 33,554,432
    unsigned short* Wot = (unsigned short*)(ws + 100663296);   //  8,388,608
    unsigned short* Qb  = (unsigned short*)(ws + 109051904);   // 67,108,864
    unsigned short* Kb  = (unsigned short*)(ws + 176160768);   // 67,108,864
    unsigned short* Vb  = (unsigned short*)(ws + 243269632);   // 67,108,864
    unsigned short* Ub  = (unsigned short*)(ws + 310378496);   // 67,108,864
    float*          KVt = (float*)(ws + 377487360);            //  4,194,304
    int*            flag= (int*)(ws + 381681664);              //  4
    unsigned short* Ob  = Xb;  // Xb dead after gemm_qkvu; reuse for normed output

    probe_dtype<<<1, 256, 0, stream>>>((const unsigned short*)d_in[0], flag);
    wconvert<<<dim3(64, 64, 5), dim3(32, 8), 0, stream>>>(d_in[1], d_in[2], d_in[3],
                                                          d_in[4], d_in[5], Wt4, Wot, flag);
    xconvert<<<16384, 256, 0, stream>>>(d_in[0], Xb, flag);
    gemm_qkvu<<<dim3(128, 64), 256, 0, stream>>>(Xb, Wt4, Qb, Kb, Vb, Ub);
    hipMemsetAsync(KVt, 0, 4194304, stream);
    kv_accum<<<dim3(64, 8), 256, 0, stream>>>(Kb, Vb, KVt);
    o_norm<<<dim3(32, 64), 256, 0, stream>>>(Qb, Ub, KVt, Ob);
    gemm_out<<<dim3(128, 16), 256, 0, stream>>>(Ob, Wot, d_out, flag);
}

// Round 2
// 1108.828 us; speedup vs baseline: 1.3959x; 1.3959x over previous
//
#include <hip/hip_runtime.h>
#include <hip/hip_bf16.h>
#include <cstdint>

// MHRetention: x[4,4096,2048] ; Wq,Wk,Wv,Wu,Wo [2048,2048] (stored [in,out])
// q,k = relu(xW)/sqrt(128); u = silu(xWu); kv = sum_l k^T v per (b,h);
// o = srms_norm(q @ kv) * u ; y = o @ Wo
// N=16384 tokens, D=2048, H=16, dh=128.

typedef __attribute__((ext_vector_type(8))) short short8;
typedef __attribute__((ext_vector_type(4))) float f32x4;

#define DEVI static __device__ __forceinline__

DEVI float bf2f(unsigned short u) {
    union { unsigned int i; float f; } w; w.i = ((unsigned int)u) << 16; return w.f;
}
DEVI unsigned short f2bf(float f) {
    union { float f; unsigned int i; } w; w.f = f;
    return (unsigned short)((w.i + 0x7fffu + ((w.i >> 16) & 1u)) >> 16);  // RNE
}

// global -> LDS direct DMA, 16B per lane. LDS dest is wave-uniform base + lane*16.
#define GLDS16(gp, lp) __builtin_amdgcn_global_load_lds( \
    (const __attribute__((address_space(1))) void*)(gp), \
    (__attribute__((address_space(3))) void*)(lp), 16, 0, 0)

// ---------------------------------------------------------------- dtype probe
__global__ void probe_dtype(const unsigned short* __restrict__ x, int* flag) {
    __shared__ int cnt;
    if (threadIdx.x == 0) cnt = 0;
    __syncthreads();
    int c = 0;
    for (int i = threadIdx.x; i < 4096; i += 256) {
        float a = fabsf(bf2f(x[i]));
        if (!(a <= 1e4f) || (a != 0.0f && a < 1e-4f)) ++c;
    }
    atomicAdd(&cnt, c);
    __syncthreads();
    if (threadIdx.x == 0) *flag = (cnt < 512) ? 1 : 0;
}

// ------------------------------------------------- weight transpose + convert
__global__ void wconvert(const void* __restrict__ Wq, const void* __restrict__ Wk,
                         const void* __restrict__ Wv, const void* __restrict__ Wu,
                         const void* __restrict__ Wo,
                         unsigned short* __restrict__ wt4,
                         unsigned short* __restrict__ wot,
                         const int* __restrict__ flag) {
    const int z = blockIdx.z;
    const void* W = (z == 0) ? Wq : (z == 1) ? Wk : (z == 2) ? Wv : (z == 3) ? Wu : Wo;
    const bool isbf = (*flag != 0);
    __shared__ float tile[32][33];
    const int j0 = blockIdx.x * 32, i0 = blockIdx.y * 32;
    const int tx = threadIdx.x, ty = threadIdx.y;  // (32,8)
#pragma unroll
    for (int r = 0; r < 4; ++r) {
        const int i = i0 + ty * 4 + r;
        float v;
        if (isbf) v = bf2f(((const unsigned short*)W)[i * 2048 + j0 + tx]);
        else      v = ((const float*)W)[i * 2048 + j0 + tx];
        tile[ty * 4 + r][tx] = v;
    }
    __syncthreads();
#pragma unroll
    for (int r = 0; r < 4; ++r) {
        const int j = j0 + ty * 4 + r;
        const unsigned short bv = f2bf(tile[tx][ty * 4 + r]);  // = W[i0+tx][j]
        if (z < 4) wt4[(long)(z * 2048 + j) * 2048 + i0 + tx] = bv;
        else       wot[(long)j * 2048 + i0 + tx] = bv;
    }
}

// ------------------------------------------------------------- x -> bf16
__global__ void xconvert(const void* __restrict__ X, unsigned short* __restrict__ xb,
                         const int* __restrict__ flag) {
    const bool isbf = (*flag != 0);
    const long i = (long)blockIdx.x * 256 + threadIdx.x;
    if (isbf) {
        ((uint4*)xb)[i] = ((const uint4*)X)[i];
    } else {
        const float4 f0 = ((const float4*)X)[2 * i];
        const float4 f1 = ((const float4*)X)[2 * i + 1];
        union { unsigned short us[8]; uint4 v; } o;
        o.us[0] = f2bf(f0.x); o.us[1] = f2bf(f0.y); o.us[2] = f2bf(f0.z); o.us[3] = f2bf(f0.w);
        o.us[4] = f2bf(f1.x); o.us[5] = f2bf(f1.y); o.us[6] = f2bf(f1.z); o.us[7] = f2bf(f1.w);
        ((uint4*)xb)[i] = o.v;
    }
}

// ---------------------------------------------- fused QKVU projection GEMM
// C[m,j] = sum_k Xb[m,k] * Wt4[j,k],  m<16384, j<8192, K=2048.
// 128x128 tile, BK=32, 4 waves, 16x16x32 MFMA. Flat grid 8192 with bijective
// XCD swizzle; ordering puts an L2-resident 4MB B-panel per XCD, A via L3.
__global__ void gemm_qkvu(const unsigned short* __restrict__ Xb,
                          const unsigned short* __restrict__ Wt4,
                          unsigned short* __restrict__ Qb, unsigned short* __restrict__ Kb,
                          unsigned short* __restrict__ Vb, unsigned short* __restrict__ Ub) {
    __shared__ unsigned short As[128 * 32];
    __shared__ unsigned short Bs[128 * 32];
    const int orig = blockIdx.x;                 // 0..8191
    const int swz = (orig & 7) * 1024 + (orig >> 3);
    const int m0 = (swz & 127) * 128;
    const int nt = swz >> 7;                     // 0..63
    const int j0 = nt * 128;
    const int tid = threadIdx.x;
    const int wave = tid >> 6, lane = tid & 63;
    const int wr = wave >> 1, wc = wave & 1;
    const int srow = tid >> 2;
    const int scol = (tid & 3) * 8;
    f32x4 acc[4][4] = {};

    for (int kt = 0; kt < 64; ++kt) {
        __syncthreads();
        const int kb = kt * 32;
#pragma unroll
        for (int i = 0; i < 2; ++i) {
            GLDS16(Xb  + (long)(m0 + i * 64 + srow) * 2048 + kb + scol, As + i * 2048 + wave * 512);
            GLDS16(Wt4 + (long)(j0 + i * 64 + srow) * 2048 + kb + scol, Bs + i * 2048 + wave * 512);
        }
        __syncthreads();
        short8 a[4], b[4];
#pragma unroll
        for (int fm = 0; fm < 4; ++fm)
            a[fm] = *(const short8*)(As + (wr * 64 + fm * 16 + (lane & 15)) * 32 + (lane >> 4) * 8);
#pragma unroll
        for (int fn = 0; fn < 4; ++fn)
            b[fn] = *(const short8*)(Bs + (wc * 64 + fn * 16 + (lane & 15)) * 32 + (lane >> 4) * 8);
#pragma unroll
        for (int fm = 0; fm < 4; ++fm)
#pragma unroll
            for (int fn = 0; fn < 4; ++fn)
                acc[fm][fn] = __builtin_amdgcn_mfma_f32_16x16x32_bf16(a[fm], b[fn], acc[fm][fn], 0, 0, 0);
    }

    const int seg = nt >> 4;  // 0..3
    unsigned short* outp = (seg == 0) ? Qb : (seg == 1) ? Kb : (seg == 2) ? Vb : Ub;
    const int cl0 = (nt & 15) * 128 + wc * 64;
#pragma unroll
    for (int fm = 0; fm < 4; ++fm) {
#pragma unroll
        for (int fn = 0; fn < 4; ++fn) {
            const int col = cl0 + fn * 16 + (lane & 15);
#pragma unroll
            for (int r = 0; r < 4; ++r) {
                const long row = m0 + wr * 64 + fm * 16 + ((lane >> 4) << 2) + r;
                float v = acc[fm][fn][r];
                if (seg <= 1)      v = fmaxf(v, 0.0f) * 0.08838834764831845f;  // relu/sqrt(128)
                else if (seg == 3) v = v / (1.0f + __expf(-v));                // silu
                outp[row * 2048 + col] = f2bf(v);
            }
        }
    }
}

// --------------------------------------------- KV state via MFMA
// KVt[dv][dk] = sum_l V[l,dv]*K[l,dk] per (b,h).  C[m=dv][j=dk]: A=V^T, B=K^T
// both staged transposed in LDS ([d][l], XOR-swizzled), bf16 MFMA w/ fp32 acc
// (products exact). 64 bh x 4 L-chunks; partials to global fp32, no atomics.
__global__ void kv_accum(const unsigned short* __restrict__ Kb,
                         const unsigned short* __restrict__ Vb,
                         float* __restrict__ KVpart) {
    __shared__ unsigned short Kt[128 * 64];  // [dk][l], swizzled
    __shared__ unsigned short Vt[128 * 64];  // [dv][l], swizzled
    const int bh = blockIdx.x;      // 64
    const int chunk = blockIdx.y;   // 4 chunks of 1024 rows
    const int b = bh >> 4, h = bh & 15;
    const int t = threadIdx.x, wave = t >> 6, lane = t & 63;
    const int wr = wave >> 1, wc = wave & 1;
    const int l0 = (t & 15) * 4;    // 4 consecutive l per thread
    const int dkg = t >> 4;         // dk block: dkg*8 .. +8
    const long gbase = ((long)b * 4096 + chunk * 1024) * 2048 + h * 128;
    f32x4 acc[4][4] = {};

    for (int tile = 0; tile < 16; ++tile) {
        __syncthreads();
        short8 kr[4], vr[4];
#pragma unroll
        for (int li = 0; li < 4; ++li) {
            const long go = gbase + (long)(tile * 64 + l0 + li) * 2048 + dkg * 8;
            kr[li] = *(const short8*)(Kb + go);
            vr[li] = *(const short8*)(Vb + go);
        }
#pragma unroll
        for (int i = 0; i < 8; ++i) {
            const int row = dkg * 8 + i;
            const int lin = row * 128 + l0 * 2;               // byte offset in [128][64] bf16
            const int off = (lin ^ ((row & 7) << 4)) >> 1;    // ushort index, swizzled
            union { unsigned short us[4]; unsigned long long u; } pk, pv;
#pragma unroll
            for (int li = 0; li < 4; ++li) { pk.us[li] = (unsigned short)kr[li][i]; pv.us[li] = (unsigned short)vr[li][i]; }
            *(unsigned long long*)(Kt + off) = pk.u;
            *(unsigned long long*)(Vt + off) = pv.u;
        }
        __syncthreads();
#pragma unroll
        for (int ks = 0; ks < 2; ++ks) {
            const int kof = ks * 64 + (lane >> 4) * 16;  // byte offset within row
            short8 a[4], bfr[4];
#pragma unroll
            for (int f = 0; f < 4; ++f) {
                const int ra = wr * 64 + f * 16 + (lane & 15);
                const int rb = wc * 64 + f * 16 + (lane & 15);
                a[f]   = *(const short8*)(Vt + (((ra * 128 + kof) ^ ((ra & 7) << 4)) >> 1));
                bfr[f] = *(const short8*)(Kt + (((rb * 128 + kof) ^ ((rb & 7) << 4)) >> 1));
            }
#pragma unroll
            for (int fm = 0; fm < 4; ++fm)
#pragma unroll
                for (int fn = 0; fn < 4; ++fn)
                    acc[fm][fn] = __builtin_amdgcn_mfma_f32_16x16x32_bf16(a[fm], bfr[fn], acc[fm][fn], 0, 0, 0);
        }
    }
    float* dst = KVpart + ((long)chunk * 64 + bh) * 16384;
#pragma unroll
    for (int fm = 0; fm < 4; ++fm)
#pragma unroll
        for (int fn = 0; fn < 4; ++fn)
#pragma unroll
            for (int r = 0; r < 4; ++r) {
                const int dv = wr * 64 + fm * 16 + ((lane >> 4) << 2) + r;
                const int dk = wc * 64 + fn * 16 + (lane & 15);
                dst[dv * 128 + dk] = acc[fm][fn][r];
            }
}

// ------------------------------- sum partials, emit bf16 hi/lo split (once)
__global__ void kv_finalize(const float* __restrict__ KVpart,
                            unsigned short* __restrict__ KVhi,
                            unsigned short* __restrict__ KVlo) {
    const long base = ((long)blockIdx.x * 256 + threadIdx.x) * 4;  // 1024 blocks
    float4 s0 = *(const float4*)(KVpart + base);
    const float4 s1 = *(const float4*)(KVpart + 1048576 + base);
    const float4 s2 = *(const float4*)(KVpart + 2097152 + base);
    const float4 s3 = *(const float4*)(KVpart + 3145728 + base);
    float s[4] = { s0.x + s1.x + s2.x + s3.x, s0.y + s1.y + s2.y + s3.y,
                   s0.z + s1.z + s2.z + s3.z, s0.w + s1.w + s2.w + s3.w };
    union { unsigned short us[4]; unsigned long long u; } hi, lo;
#pragma unroll
    for (int j = 0; j < 4; ++j) {
        hi.us[j] = f2bf(s[j]);
        lo.us[j] = f2bf(s[j] - bf2f(hi.us[j]));
    }
    *(unsigned long long*)(KVhi + base) = hi.u;
    *(unsigned long long*)(KVlo + base) = lo.u;
}

// ------------------------- O = Q @ KV, SRMS-norm over dh, * u, -> bf16 Ob
// KV consumed as precomputed bf16 hi+lo (2 MFMAs each) from L2-hot buffers.
__global__ void o_norm(const unsigned short* __restrict__ Qb,
                       const unsigned short* __restrict__ Ub,
                       const unsigned short* __restrict__ KVhi,
                       const unsigned short* __restrict__ KVlo,
                       unsigned short* __restrict__ Ob) {
    __shared__ unsigned short Qs[128 * 128];
    const int tid = threadIdx.x, wave = tid >> 6, lane = tid & 63;
    const int tile = blockIdx.x;   // 0..31
    const int bh = blockIdx.y;     // 0..63
    const int b = bh >> 4, h = bh & 15;
    const long n0 = (long)b * 4096 + tile * 128;

    const int qrow = tid >> 4;
    const int qcol = (tid & 15) * 8;
#pragma unroll
    for (int i = 0; i < 8; ++i)
        GLDS16(Qb + (n0 + i * 16 + qrow) * 2048 + h * 128 + qcol, Qs + i * 2048 + wave * 512);
    __syncthreads();

    const unsigned short* KH = KVhi + (long)bh * 16384;
    const unsigned short* KL = KVlo + (long)bh * 16384;
    f32x4 acc[2][8] = {};
#pragma unroll
    for (int kk = 0; kk < 4; ++kk) {
        const short8 a0 = *(const short8*)(Qs + (wave * 32 + (lane & 15)) * 128 + kk * 32 + (lane >> 4) * 8);
        const short8 a1 = *(const short8*)(Qs + (wave * 32 + 16 + (lane & 15)) * 128 + kk * 32 + (lane >> 4) * 8);
#pragma unroll
        for (int fn = 0; fn < 8; ++fn) {
            const int bo = (fn * 16 + (lane & 15)) * 128 + kk * 32 + (lane >> 4) * 8;
            const short8 bhi = *(const short8*)(KH + bo);
            const short8 blo = *(const short8*)(KL + bo);
            acc[0][fn] = __builtin_amdgcn_mfma_f32_16x16x32_bf16(a0, bhi, acc[0][fn], 0, 0, 0);
            acc[0][fn] = __builtin_amdgcn_mfma_f32_16x16x32_bf16(a0, blo, acc[0][fn], 0, 0, 0);
            acc[1][fn] = __builtin_amdgcn_mfma_f32_16x16x32_bf16(a1, bhi, acc[1][fn], 0, 0, 0);
            acc[1][fn] = __builtin_amdgcn_mfma_f32_16x16x32_bf16(a1, blo, acc[1][fn], 0, 0, 0);
        }
    }

#pragma unroll
    for (int fm = 0; fm < 2; ++fm) {
#pragma unroll
        for (int r = 0; r < 4; ++r) {
            float ssq = 0.0f;
#pragma unroll
            for (int fn = 0; fn < 8; ++fn) { const float v = acc[fm][fn][r]; ssq += v * v; }
            ssq += __shfl_xor(ssq, 1);
            ssq += __shfl_xor(ssq, 2);
            ssq += __shfl_xor(ssq, 4);
            ssq += __shfl_xor(ssq, 8);
            const float nrm = fmaxf(sqrtf(ssq) * 0.08838834764831845f, 1e-12f);
            const float scl = 1.0f / nrm;
            const long row = n0 + wave * 32 + fm * 16 + ((lane >> 4) << 2) + r;
#pragma unroll
            for (int fn = 0; fn < 8; ++fn) {
                const int col = fn * 16 + (lane & 15);
                const float uv = bf2f(Ub[row * 2048 + h * 128 + col]);
                Ob[row * 2048 + h * 128 + col] = f2bf(acc[fm][fn][r] * scl * uv);
            }
        }
    }
}

// ------------------------------------------------------- output projection
__global__ void gemm_out(const unsigned short* __restrict__ Obuf,
                         const unsigned short* __restrict__ Wot,
                         void* __restrict__ out, const int* __restrict__ flag) {
    __shared__ unsigned short As[128 * 32];
    __shared__ unsigned short Bs[128 * 32];
    const int orig = blockIdx.x;                 // 0..2047
    const int swz = (orig & 7) * 256 + (orig >> 3);
    const int m0 = (swz & 127) * 128;
    const int j0 = (swz >> 7) * 128;             // 0..15 tiles
    const int tid = threadIdx.x;
    const int wave = tid >> 6, lane = tid & 63;
    const int wr = wave >> 1, wc = wave & 1;
    const int srow = tid >> 2;
    const int scol = (tid & 3) * 8;
    f32x4 acc[4][4] = {};

    for (int kt = 0; kt < 64; ++kt) {
        __syncthreads();
        const int kb = kt * 32;
#pragma unroll
        for (int i = 0; i < 2; ++i) {
            GLDS16(Obuf + (long)(m0 + i * 64 + srow) * 2048 + kb + scol, As + i * 2048 + wave * 512);
            GLDS16(Wot  + (long)(j0 + i * 64 + srow) * 2048 + kb + scol, Bs + i * 2048 + wave * 512);
        }
        __syncthreads();
        short8 a[4], b[4];
#pragma unroll
        for (int fm = 0; fm < 4; ++fm)
            a[fm] = *(const short8*)(As + (wr * 64 + fm * 16 + (lane & 15)) * 32 + (lane >> 4) * 8);
#pragma unroll
        for (int fn = 0; fn < 4; ++fn)
            b[fn] = *(const short8*)(Bs + (wc * 64 + fn * 16 + (lane & 15)) * 32 + (lane >> 4) * 8);
#pragma unroll
        for (int fm = 0; fm < 4; ++fm)
#pragma unroll
            for (int fn = 0; fn < 4; ++fn)
                acc[fm][fn] = __builtin_amdgcn_mfma_f32_16x16x32_bf16(a[fm], b[fn], acc[fm][fn], 0, 0, 0);
    }

    const bool isbf = (*flag != 0);
#pragma unroll
    for (int fm = 0; fm < 4; ++fm) {
#pragma unroll
        for (int fn = 0; fn < 4; ++fn) {
            const int col = j0 + wc * 64 + fn * 16 + (lane & 15);
#pragma unroll
            for (int r = 0; r < 4; ++r) {
                const long row = m0 + wr * 64 + fm * 16 + ((lane >> 4) << 2) + r;
                const float v = acc[fm][fn][r];
                if (isbf) ((unsigned short*)out)[row * 2048 + col] = f2bf(v);
                else      ((float*)out)[row * 2048 + col] = v;
            }
        }
    }
}

// ---------------------------------------------------------------- launcher
extern "C" void kernel_launch(void* const* d_in, const int* in_sizes, int n_in,
                              void* d_out, int out_size, void* d_ws, size_t ws_size,
                              hipStream_t stream) {
    (void)in_sizes; (void)n_in; (void)out_size; (void)ws_size;
    char* ws = (char*)d_ws;
    unsigned short* Xb  = (unsigned short*)(ws + 0);           // 64 MB
    unsigned short* Wt4 = (unsigned short*)(ws + 67108864);    // 32 MB
    unsigned short* Wot = (unsigned short*)(ws + 100663296);   //  8 MB
    unsigned short* Qb  = (unsigned short*)(ws + 109051904);   // 64 MB
    unsigned short* Kb  = (unsigned short*)(ws + 176160768);   // 64 MB
    unsigned short* Vb  = (unsigned short*)(ws + 243269632);   // 64 MB
    unsigned short* Ub  = (unsigned short*)(ws + 310378496);   // 64 MB
    int*            flag= (int*)(ws + 381681664);              //  4 B
    // regions reused after their producers are done:
    float*          KVpart = (float*)Wt4;                       // 16 MB (Wt4 dead after gemm_qkvu)
    unsigned short* KVhi   = (unsigned short*)(ws + 67108864 + 16777216);  // 2 MB
    unsigned short* KVlo   = (unsigned short*)(ws + 67108864 + 18874368);  // 2 MB
    unsigned short* Ob     = Xb;                                // Xb dead after gemm_qkvu

    probe_dtype<<<1, 256, 0, stream>>>((const unsigned short*)d_in[0], flag);
    wconvert<<<dim3(64, 64, 5), dim3(32, 8), 0, stream>>>(d_in[1], d_in[2], d_in[3],
                                                          d_in[4], d_in[5], Wt4, Wot, flag);
    xconvert<<<16384, 256, 0, stream>>>(d_in[0], Xb, flag);
    gemm_qkvu<<<8192, 256, 0, stream>>>(Xb, Wt4, Qb, Kb, Vb, Ub);
    kv_accum<<<dim3(64, 4), 256, 0, stream>>>(Kb, Vb, KVpart);
    kv_finalize<<<1024, 256, 0, stream>>>(KVpart, KVhi, KVlo);
    o_norm<<<dim3(32, 64), 256, 0, stream>>>(Qb, Ub, KVhi, KVlo, Ob);
    gemm_out<<<2048, 256, 0, stream>>>(Ob, Wot, d_out, flag);
}